// Round 1
// baseline (203.848 us; speedup 1.0000x reference)
//
#include <hip/hip_runtime.h>

#define D1 96
#define GRID_VOX (D1 * D1 * D1)

// ---------------------------------------------------------------------------
// Scatter active voxel indices into dense level-1 lookup grid (pre-memset -1)
// ---------------------------------------------------------------------------
__global__ void scatter_grid_kernel(const int* __restrict__ coords,
                                    int* __restrict__ grid, int n) {
    int i = blockIdx.x * blockDim.x + threadIdx.x;
    if (i < n) {
        int c0 = coords[3 * i], c1 = coords[3 * i + 1], c2 = coords[3 * i + 2];
        grid[(c0 * D1 + c1) * D1 + c2] = i;
    }
}

// ---------------------------------------------------------------------------
// Build folded conv2 weights: W2eff[s][d] = sum of W2[o] over o mapping to
// parent-offset slot d for child s.  64 blocks (s*8+d), 256 threads.
// Per axis: p = s-1+d; o in [max(-1, 2p-s), min(1, 2p+1-s)]
// ---------------------------------------------------------------------------
__global__ void build_w2eff_kernel(const float* __restrict__ W2,
                                   float* __restrict__ Weff) {
    int sd = blockIdx.x;
    int s = sd >> 3, d = sd & 7;
    int sa[3] = { (s >> 2) & 1, (s >> 1) & 1, s & 1 };
    int da[3] = { (d >> 2) & 1, (d >> 1) & 1, d & 1 };
    int lo[3], hi[3];
#pragma unroll
    for (int a = 0; a < 3; ++a) {
        int p = sa[a] - 1 + da[a];
        int l = 2 * p - sa[a];
        int h = 2 * p + 1 - sa[a];
        lo[a] = l < -1 ? -1 : l;
        hi[a] = h > 1 ? 1 : h;
    }
    for (int e = threadIdx.x; e < 4096; e += blockDim.x) {
        float sum = 0.0f;
        for (int o0 = lo[0]; o0 <= hi[0]; ++o0)
            for (int o1 = lo[1]; o1 <= hi[1]; ++o1)
                for (int o2 = lo[2]; o2 <= hi[2]; ++o2) {
                    int k = (o0 + 1) * 9 + (o1 + 1) * 3 + (o2 + 1);
                    sum += W2[k * 4096 + e];
                }
        Weff[sd * 4096 + e] = sum;
    }
}

// ---------------------------------------------------------------------------
// Conv1 + SiLU: one 64-lane wave per active voxel. lane = output channel.
// ---------------------------------------------------------------------------
__global__ __launch_bounds__(64) void conv1_kernel(
    const int* __restrict__ coords, const float* __restrict__ feats,
    const float* __restrict__ W1, const float* __restrict__ b1,
    const int* __restrict__ grid, float* __restrict__ h, int n) {
    int v = blockIdx.x;
    int lane = threadIdx.x;
    int c0 = coords[3 * v], c1 = coords[3 * v + 1], c2 = coords[3 * v + 2];

    // lanes 0..26 each look up one neighbor
    int nb = -1;
    if (lane < 27) {
        int o0 = lane / 9 - 1, o1 = (lane / 3) % 3 - 1, o2 = lane % 3 - 1;
        int x0 = c0 + o0, x1 = c1 + o1, x2 = c2 + o2;
        if ((unsigned)x0 < D1 && (unsigned)x1 < D1 && (unsigned)x2 < D1)
            nb = grid[(x0 * D1 + x1) * D1 + x2];
    }

    float acc = b1[lane];
    for (int k = 0; k < 27; ++k) {
        int idx = __shfl(nb, k);
        if (idx >= 0) {  // wave-uniform branch
            float f = feats[idx * 64 + lane];
            const float* w = W1 + k * 4096 + lane;
#pragma unroll
            for (int ci = 0; ci < 64; ++ci)
                acc += __shfl(f, ci) * w[ci * 64];
        }
    }
    acc = acc / (1.0f + __expf(-acc));  // SiLU
    h[v * 64 + lane] = acc;
}

// ---------------------------------------------------------------------------
// Conv2 + SiLU at level 2 via parent-grid lookups + folded weights.
// grid = dim3(n, 8): blockIdx.x = parent i, blockIdx.y = child s (s-major for
// W2eff L1 reuse across consecutive blocks). lane = output channel.
// ---------------------------------------------------------------------------
__global__ __launch_bounds__(64) void conv2_kernel(
    const int* __restrict__ coords, const float* __restrict__ h,
    const float* __restrict__ Weff, const float* __restrict__ b2,
    const int* __restrict__ grid, float* __restrict__ out, int n) {
    int i = blockIdx.x;
    int s = blockIdx.y;
    int lane = threadIdx.x;
    int c0 = coords[3 * i], c1 = coords[3 * i + 1], c2 = coords[3 * i + 2];
    int s0 = (s >> 2) & 1, s1 = (s >> 1) & 1, s2 = s & 1;

    // lanes 0..7 each look up one parent-slot neighbor
    int nb = -1;
    if (lane < 8) {
        int d0 = (lane >> 2) & 1, d1 = (lane >> 1) & 1, d2 = lane & 1;
        int x0 = c0 + s0 - 1 + d0;
        int x1 = c1 + s1 - 1 + d1;
        int x2 = c2 + s2 - 1 + d2;
        if ((unsigned)x0 < D1 && (unsigned)x1 < D1 && (unsigned)x2 < D1)
            nb = grid[(x0 * D1 + x1) * D1 + x2];
    }

    float acc = b2[lane];
    const float* Ws = Weff + s * 8 * 4096;
    for (int d = 0; d < 8; ++d) {
        int idx = __shfl(nb, d);
        if (idx >= 0) {  // wave-uniform branch
            float f = h[idx * 64 + lane];
            const float* w = Ws + d * 4096 + lane;
#pragma unroll
            for (int ci = 0; ci < 64; ++ci)
                acc += __shfl(f, ci) * w[ci * 64];
        }
    }
    acc = acc / (1.0f + __expf(-acc));  // SiLU
    out[(i * 8 + s) * 64 + lane] = acc;
}

// ---------------------------------------------------------------------------
extern "C" void kernel_launch(void* const* d_in, const int* in_sizes, int n_in,
                              void* d_out, int out_size, void* d_ws,
                              size_t ws_size, hipStream_t stream) {
    const int* coords = (const int*)d_in[0];
    const float* feats = (const float*)d_in[1];
    const float* W1 = (const float*)d_in[2];
    const float* b1 = (const float*)d_in[3];
    const float* W2 = (const float*)d_in[4];
    const float* b2 = (const float*)d_in[5];
    float* out = (float*)d_out;

    int n = in_sizes[0] / 3;  // 20000

    // workspace layout
    char* ws = (char*)d_ws;
    int* grid1 = (int*)ws;                                   // 96^3 ints = 3.54 MB
    float* h = (float*)(ws + (size_t)GRID_VOX * 4);          // n*64 f32 = 5.12 MB
    float* w2eff = h + (size_t)n * 64;                       // 64*4096 f32 = 1 MB

    // 1. clear + scatter level-1 grid (0xFF bytes == -1 int32)
    hipMemsetAsync(grid1, 0xFF, (size_t)GRID_VOX * 4, stream);
    scatter_grid_kernel<<<(n + 255) / 256, 256, 0, stream>>>(coords, grid1, n);

    // 2. fold conv2 weights
    build_w2eff_kernel<<<64, 256, 0, stream>>>(W2, w2eff);

    // 3. conv1 + SiLU
    conv1_kernel<<<n, 64, 0, stream>>>(coords, feats, W1, b1, grid1, h, n);

    // 4. conv2 (via parent grid) + SiLU
    conv2_kernel<<<dim3(n, 8), 64, 0, stream>>>(coords, h, w2eff, b2, grid1,
                                                out, n);
}